// Round 12
// baseline (353.150 us; speedup 1.0000x reference)
//
#include <hip/hip_runtime.h>

// LoRALinear: out[8192,4096] = x @ W.T + 2.0*(x@A.T)@B.T = x @ (W + 2*B@A).T
// One bf16 MFMA GEMM. Round-12 structure: 256x128 tile, 8 waves (4x2),
// BK=32, 2-buffer LDS (48KB) -> ~116 regs/wave -> 2 BLOCKS/CU resident.
// Simple m97-style loop (stage -> read -> MFMA -> vmcnt(0) -> barrier);
// cross-block TLP overlaps one block's drains with the other's compute.

#define N_ROWS 8192
#define K_DIM  4096
#define N_COLS 4096
#define RANK   16
#define BKS    32
#define NSTEP  (K_DIM / BKS)   // 128 K-steps

#define XBLK ((N_ROWS * K_DIM / 4) / 256)   // 32768 blocks for x->bf16
#define WBLK ((N_COLS * K_DIM / 4) / 256)   // 16384 blocks for W_eff->bf16

typedef __bf16 bf16x8 __attribute__((ext_vector_type(8)));
typedef float  f32x4  __attribute__((ext_vector_type(4)));

__device__ __forceinline__ unsigned short f2bf(float f) {
  unsigned int u = __builtin_bit_cast(unsigned int, f);
  u += 0x7FFFu + ((u >> 16) & 1u);   // RNE
  return (unsigned short)(u >> 16);
}

// ---------------- fused conversion kernel ----------------

__global__ __launch_bounds__(256) void prep_kernel(const float* __restrict__ x,
                                                   const float* __restrict__ w,
                                                   const float* __restrict__ A,
                                                   const float* __restrict__ Bm,
                                                   unsigned short* __restrict__ xb,
                                                   unsigned short* __restrict__ wb) {
  const int b = blockIdx.x;
  if (b < XBLK) {
    size_t idx = (size_t)b * 256 + threadIdx.x;
    const float4 v = *reinterpret_cast<const float4*>(x + idx * 4);
    ushort4 r;
    r.x = f2bf(v.x); r.y = f2bf(v.y); r.z = f2bf(v.z); r.w = f2bf(v.w);
    *reinterpret_cast<ushort4*>(xb + idx * 4) = r;
  } else {
    size_t idx = (size_t)(b - XBLK) * 256 + threadIdx.x;
    int o  = (int)(idx >> 10);
    int ic = (int)(idx & 1023) << 2;
    const float4 wv = *reinterpret_cast<const float4*>(w + (size_t)o * K_DIM + ic);
    float a0 = wv.x, a1 = wv.y, a2 = wv.z, a3 = wv.w;
    float br[RANK];
#pragma unroll
    for (int r4 = 0; r4 < RANK / 4; ++r4) {
      const float4 bv = *reinterpret_cast<const float4*>(Bm + (size_t)o * RANK + r4 * 4);
      br[r4 * 4 + 0] = bv.x; br[r4 * 4 + 1] = bv.y;
      br[r4 * 4 + 2] = bv.z; br[r4 * 4 + 3] = bv.w;
    }
#pragma unroll
    for (int r = 0; r < RANK; ++r) {
      const float4 av = *reinterpret_cast<const float4*>(A + (size_t)r * K_DIM + ic);
      float b2 = br[r] * 2.0f;
      a0 += b2 * av.x; a1 += b2 * av.y; a2 += b2 * av.z; a3 += b2 * av.w;
    }
    ushort4 rr;
    rr.x = f2bf(a0); rr.y = f2bf(a1); rr.z = f2bf(a2); rr.w = f2bf(a3);
    *reinterpret_cast<ushort4*>(wb + (size_t)o * K_DIM + ic) = rr;
  }
}

// ---------------- GEMM ----------------
// LDS per buffer (24576 B): A 16KB (256 rows x 32 k) @0, B 8KB (128 x 32) @16384.
// Two buffers at 0 / 24576; total 48KB -> 2 blocks/CU.
// Pair swizzle (R10-verified): row R, k-granule g (16B):
//   byte = (R>>1)*128 + ((((R&1)<<2)|g) ^ ((R>>1)&7))*16
// Staged via pre-swizzled global source (linear gload_lds dest):
//   thread t -> byte t*16: p=t>>3, slot=t&7, slog=slot^(p&7),
//   row = 2p + (slog>>2), k = (slog&3)*8.   (A second gload: +128 rows, +8192B)
// Waves: wr=wv>>1 (0..3, 64-row slabs), wc=wv&1 (0..1, 64-col slabs).
// Frags (mf,nf 0..3): A row = wr*64+mf*16+lr  -> wr*4096 + mf*1024 + lane_off
//                     B row = wc*64+nf*16+lr  -> 16384 + wc*4096 + nf*1024 + lane_off
// (p&7 == lr>>1 since wr*32, mf*8, wc*32, nf*8 all == 0 mod 8.)

__device__ __forceinline__ void gload_lds16(const void* g, void* l) {
  __builtin_amdgcn_global_load_lds(
      (__attribute__((address_space(1))) void*)g,
      (__attribute__((address_space(3))) void*)l, 16, 0, 0);
}

__global__ __launch_bounds__(512, 4) void gemm_bf16_r12(
    const unsigned short* __restrict__ xb, const unsigned short* __restrict__ wb,
    float* __restrict__ out) {
  __shared__ __align__(16) char smem[49152];

  const int t  = threadIdx.x;
  const int l  = t & 63;
  const int wv = t >> 6;
  const int lr = l & 15;
  const int lk = l >> 4;
  const int wr = wv >> 1;     // 0..3
  const int wc = wv & 1;      // 0..1

  // XCD-aware bijective swizzle: 1024 blocks % 8 == 0
  const int bid  = blockIdx.x;
  const int sbid = (bid & 7) * 128 + (bid >> 3);
  const int bm   = sbid >> 5;   // 0..31  (row-block of 256)
  const int bn   = sbid & 31;   // 0..31  (col-block of 128)

  // staging source (pre-swizzled, R10-verified map)
  const int slog  = (t & 7) ^ ((t >> 3) & 7);
  const int s_row = 2 * (t >> 3) + (slog >> 2);    // 0..127
  const int s_k   = (slog & 3) * 8;                // 0,8,16,24
  const unsigned short* gA = xb + (size_t)(bm * 256 + s_row) * K_DIM + s_k;
  const unsigned short* gB = wb + (size_t)(bn * 128 + s_row) * K_DIM + s_k;
  char* ldsA = smem + t * 16;            // + buf offset; second half +8192
  char* ldsB = smem + 16384 + t * 16;    // + buf offset

#define STG(BUFB, KT) do {                                                      \
    const unsigned short* _ga = gA + (size_t)(KT) * BKS;                        \
    const unsigned short* _gb = gB + (size_t)(KT) * BKS;                        \
    gload_lds16(_ga, ldsA + (BUFB));                                            \
    gload_lds16(_ga + (size_t)128 * K_DIM, ldsA + (BUFB) + 8192);               \
    gload_lds16(_gb, ldsB + (BUFB));                                            \
  } while (0)

  // fragment read addressing (R10-verified lane term)
  const int lane_off = (lr >> 1) * 128 + (((((lr & 1) << 2) | lk) ^ (lr >> 1)) << 4);
  const int a_base = wr * 4096 + lane_off;           // + mf*1024
  const int b_base = 16384 + wc * 4096 + lane_off;   // + nf*1024

  bf16x8 aF[4], bF[4];
  f32x4 acc[4][4];
#pragma unroll
  for (int m = 0; m < 4; ++m)
#pragma unroll
    for (int n = 0; n < 4; ++n)
      acc[m][n] = (f32x4){0.f, 0.f, 0.f, 0.f};

#define RD(BUFB) do {                                                           \
    _Pragma("unroll")                                                           \
    for (int m = 0; m < 4; ++m)                                                 \
      aF[m] = *(const bf16x8*)(smem + (BUFB) + a_base + m * 1024);              \
    _Pragma("unroll")                                                           \
    for (int n = 0; n < 4; ++n)                                                 \
      bF[n] = *(const bf16x8*)(smem + (BUFB) + b_base + n * 1024);              \
  } while (0)

#define MF() do {                                                               \
    _Pragma("unroll")                                                           \
    for (int m = 0; m < 4; ++m)                                                 \
      _Pragma("unroll")                                                         \
      for (int n = 0; n < 4; ++n)                                               \
        acc[m][n] = __builtin_amdgcn_mfma_f32_16x16x32_bf16(                    \
            aF[m], bF[n], acc[m][n], 0, 0, 0);                                  \
  } while (0)

// one K-step: stage next -> buf NB, read cur from CB, 16 independent MFMAs,
// drain own stages, barrier. Cross-block TLP hides the drain.
#define STEP(CB, NB, T) do {                                                    \
    const int _t1 = ((T) + 1 < NSTEP) ? (T) + 1 : NSTEP - 1;                    \
    STG(NB, _t1);                                                               \
    RD(CB);                                                                     \
    __builtin_amdgcn_s_setprio(1);                                              \
    MF();                                                                       \
    __builtin_amdgcn_s_setprio(0);                                              \
    __builtin_amdgcn_sched_barrier(0);                                          \
    asm volatile("s_waitcnt vmcnt(0)");                                         \
    __builtin_amdgcn_s_barrier();                                               \
    __builtin_amdgcn_sched_barrier(0);                                          \
  } while (0)

  // prologue: stage step 0 -> buf0; drain; barrier
  STG(0, 0);
  __builtin_amdgcn_sched_barrier(0);
  asm volatile("s_waitcnt vmcnt(0)");
  __builtin_amdgcn_s_barrier();
  __builtin_amdgcn_sched_barrier(0);

#pragma nounroll
  for (int u = 0; u < NSTEP / 2; ++u) {
    STEP(0, 24576, 2 * u);
    STEP(24576, 0, 2 * u + 1);
  }

  // epilogue: C/D layout col=lane&15, row=(lane>>4)*4+j
  const int orow = bm * 256 + wr * 64 + lk * 4;
  const int ocol = bn * 128 + wc * 64 + lr;
#pragma unroll
  for (int mf = 0; mf < 4; ++mf)
#pragma unroll
    for (int nf = 0; nf < 4; ++nf)
#pragma unroll
      for (int j = 0; j < 4; ++j)
        out[(size_t)(orow + mf * 16 + j) * N_COLS + (ocol + nf * 16)] = acc[mf][nf][j];

#undef STG
#undef RD
#undef MF
#undef STEP
}

// ---------------- exact fp32 fallback (ws too small) ----------------

__global__ __launch_bounds__(256) void fallback_kernel(const float* __restrict__ x,
                                                       const float* __restrict__ w,
                                                       const float* __restrict__ A,
                                                       const float* __restrict__ Bm,
                                                       float* __restrict__ out) {
  const int o    = blockIdx.x * 256 + threadIdx.x;
  const int nrow = blockIdx.y;
  float bro[RANK];
#pragma unroll
  for (int r = 0; r < RANK; ++r) bro[r] = Bm[(size_t)o * RANK + r] * 2.0f;
  float bacc = 0.f;
  float tacc[RANK];
#pragma unroll
  for (int r = 0; r < RANK; ++r) tacc[r] = 0.f;
  for (int k = 0; k < K_DIM; ++k) {
    float xv = x[(size_t)nrow * K_DIM + k];
    bacc += xv * w[(size_t)o * K_DIM + k];
#pragma unroll
    for (int r = 0; r < RANK; ++r) tacc[r] += xv * A[(size_t)r * K_DIM + k];
  }
  float res = bacc;
#pragma unroll
  for (int r = 0; r < RANK; ++r) res += bro[r] * tacc[r];
  out[(size_t)nrow * N_COLS + o] = res;
}

// ---------------- launch ----------------

extern "C" void kernel_launch(void* const* d_in, const int* in_sizes, int n_in,
                              void* d_out, int out_size, void* d_ws, size_t ws_size,
                              hipStream_t stream) {
  const float* x  = (const float*)d_in[0];
  const float* w  = (const float*)d_in[1];
  const float* A  = (const float*)d_in[2];
  const float* Bm = (const float*)d_in[3];
  float* out = (float*)d_out;

  const size_t need = ((size_t)N_ROWS * K_DIM + (size_t)N_COLS * K_DIM) * sizeof(unsigned short);
  if (ws_size < need) {
    dim3 grid(N_COLS / 256, N_ROWS);
    fallback_kernel<<<grid, 256, 0, stream>>>(x, w, A, Bm, out);
    return;
  }

  unsigned short* xb = (unsigned short*)d_ws;
  unsigned short* wb = xb + (size_t)N_ROWS * K_DIM;

  prep_kernel<<<XBLK + WBLK, 256, 0, stream>>>(x, w, A, Bm, xb, wb);

  const int grid_gemm = (N_ROWS / 256) * (N_COLS / 128);   // 32*32 = 1024
  gemm_bf16_r12<<<grid_gemm, 512, 0, stream>>>(xb, wb, out);
}